// Round 7
// baseline (303.644 us; speedup 1.0000x reference)
//
#include <hip/hip_runtime.h>
#include <hip/hip_fp16.h>
#include <stdint.h>

// Problem constants (fixed by the reference):
#define MQ 8192   // N*C queries
#define NK 1024   // K codewords
#define DD 1024   // H*W
// fp8-e4m3 screen: score err sigma ~2.3 (RNE quant both operands, dot over
// 1024), pairwise ~3.3 incl f16 store -> DELTA=32 ~ 9.7 sigma.
#define DELTA 32.0f

typedef _Float16 half8_t __attribute__((ext_vector_type(8)));
typedef float    floatx4 __attribute__((ext_vector_type(4)));
typedef int      intx4   __attribute__((ext_vector_type(4)));
typedef int      intx8   __attribute__((ext_vector_type(8)));

// async global->LDS, 16B per lane; LDS dest is wave-uniform base + lane*16
#define GLOAD_LDS16(gp, lp)                                                   \
  __builtin_amdgcn_global_load_lds(                                           \
      (const __attribute__((address_space(1))) void*)(gp),                    \
      (__attribute__((address_space(3))) void*)(lp), 16, 0, 0)

// ---------- prep: f32 -> fp8(e4m3) with PRE-SWIZZLED k-layout + csqr ----------
// Within each row's 128B K-chunk, byte b of the fp8 row is stored at
// b ^ ((row&7)<<4). Screen stages linearly (global_load_lds can't scatter) and
// un-XORs on the LDS read -> 16-way bank conflict becomes 2-way (free).
__global__ void k_prep(const float* __restrict__ x, const float* __restrict__ cb,
                       unsigned char* __restrict__ a8, unsigned char* __restrict__ b8,
                       float* __restrict__ csqr, unsigned* __restrict__ cnt) {
  const int bid = blockIdx.x;
  const int t = threadIdx.x;
  if (bid < 2048) {
    // queries: thread converts 16 floats -> one 16B fp8 granule
    const int gid = bid * 256 + t;
    const int row = gid >> 6, g = gid & 63;
    const float4* src = (const float4*)(x + (size_t)row * DD + g * 16);
    int w[4];
#pragma unroll
    for (int q = 0; q < 4; ++q) {
      float4 v = src[q];
      int p = __builtin_amdgcn_cvt_pk_fp8_f32(v.x, v.y, 0, false);
      p = __builtin_amdgcn_cvt_pk_fp8_f32(v.z, v.w, p, true);
      w[q] = p;
    }
    intx4 o = {w[0], w[1], w[2], w[3]};
    const int doff = (g * 16) ^ ((row & 7) << 4);
    *(intx4*)(a8 + (size_t)row * DD + doff) = o;
  } else {
    // codewords: one wave per row (4 rows/block); fp8 + exact |c|^2 in double
    if (bid == 2048 && t < 64) cnt[t] = 0;  // per-bm completion counters
    const int wv = t >> 6, lane = t & 63;
    const int k = (bid - 2048) * 4 + wv;
    const float4* src = (const float4*)(cb + (size_t)k * DD + lane * 16);
    double s = 0.0;
    int w[4];
#pragma unroll
    for (int q = 0; q < 4; ++q) {
      float4 v = src[q];
      s += (double)v.x * v.x + (double)v.y * v.y + (double)v.z * v.z + (double)v.w * v.w;
      int p = __builtin_amdgcn_cvt_pk_fp8_f32(v.x, v.y, 0, false);
      p = __builtin_amdgcn_cvt_pk_fp8_f32(v.z, v.w, p, true);
      w[q] = p;
    }
    intx4 o = {w[0], w[1], w[2], w[3]};
    const int doff = (lane * 16) ^ ((k & 7) << 4);
    *(intx4*)(b8 + (size_t)k * DD + doff) = o;
    for (int m = 32; m >= 1; m >>= 1) s += __shfl_xor(s, m, 64);
    if (lane == 0) csqr[k] = (float)(s - 1024.0);
  }
}

__device__ __forceinline__ unsigned sortable_u32(float f) {
  unsigned u = __float_as_uint(f);
  return (u & 0x80000000u) ? ~u : (u | 0x80000000u);
}

// shared refine-row body: scan S row m, candidate ballot, exact fp32 refine,
// gather winner, write output copy/copies.
__device__ __forceinline__ void refine_row(
    int m, int lane, const _Float16* __restrict__ S, const float* __restrict__ x,
    const float* __restrict__ cb, float* __restrict__ out, int both) {
  const half8_t* Srow = (const half8_t*)(S + (size_t)m * NK);
  half8_t s0 = Srow[lane * 2];
  half8_t s1 = Srow[lane * 2 + 1];
  float sc[16];
#pragma unroll
  for (int k = 0; k < 8; ++k) { sc[k] = (float)s0[k]; sc[8 + k] = (float)s1[k]; }
  float mn = sc[0];
#pragma unroll
  for (int k = 1; k < 16; ++k) mn = fminf(mn, sc[k]);
  for (int o = 1; o <= 32; o <<= 1) mn = fminf(mn, __shfl_xor(mn, o, 64));
  const float thr = mn + DELTA;

  // count candidates + remember the first (all wave-uniform; >=1 guaranteed)
  int total = 0, first = -1;
#pragma unroll
  for (int s = 0; s < 16; ++s) {
    unsigned long long msk = __ballot(sc[s] <= thr);
    if (first < 0 && msk) first = __builtin_ctzll(msk) * 16 + s;
    total += __popcll(msk);
  }

  int widx;
  if (total == 1) {
    widx = first;  // unique winner: skip x re-read + exact refine entirely
  } else {
    const float4* xr4 = (const float4*)(x + (size_t)m * DD);
    float4 xr[4];
#pragma unroll
    for (int q = 0; q < 4; ++q) xr[q] = xr4[q * 64 + lane];

    // exact fp32 refine — iterate ballot masks directly (no cap, no drop)
    unsigned long long best = ~0ULL;
    for (int s = 0; s < 16; ++s) {
      unsigned long long msk = __ballot(sc[s] <= thr);
      while (msk) {
        int l = __builtin_ctzll(msk);
        msk &= msk - 1;
        const int cnd = l * 16 + s;  // lane l holds cols l*16 + s
        const float4* c4 = (const float4*)(cb + (size_t)cnd * DD);
        float d = 0.f;
#pragma unroll
        for (int q = 0; q < 4; ++q) {
          float4 v = c4[q * 64 + lane];
          float dx = xr[q].x - v.x, dy = xr[q].y - v.y;
          float dz = xr[q].z - v.z, dw = xr[q].w - v.w;
          d += dx * dx + dy * dy + dz * dz + dw * dw;
        }
        for (int o = 1; o <= 32; o <<= 1) d += __shfl_xor(d, o, 64);
        unsigned long long key =
            ((unsigned long long)sortable_u32(d) << 32) | (unsigned)cnd;
        best = key < best ? key : best;  // ties -> lowest index (np argmin)
      }
    }
    widx = (int)(best & 0xFFFFFFFFULL);
  }

  const floatx4* w4 = (const floatx4*)(cb + (size_t)widx * DD);
  floatx4* o0 = (floatx4*)(out + (size_t)m * DD);
  floatx4* o1 = (floatx4*)(out + (size_t)(m + MQ) * DD);
#pragma unroll
  for (int q = 0; q < 4; ++q) {
    floatx4 v = w4[q * 64 + lane];
    __builtin_nontemporal_store(v, &o0[q * 64 + lane]);
    if (both) __builtin_nontemporal_store(v, &o1[q * 64 + lane]);
  }
}

// ---------------- phase A: fp8 MX screen GEMM + FUSED refine -----------------
// S[m][n] = f16(csqr[n] - 2 * dot(x8[m], c8[n])) ; 128x128 tile, 4 waves.
// After writing its S tile, each block bumps cnt[bm]; the 8th (last) arriver
// owns the now-complete 128 S rows of bm and refines them in-place (S reads
// are L2-hot: all 8 producer blocks sit on the same XCD via the swizzle).
// No spinning -> no co-residency requirement -> no deadlock risk.
__global__ __launch_bounds__(256, 2) void k_screen(
    const unsigned char* __restrict__ A8, const unsigned char* __restrict__ B8,
    const float* __restrict__ csqr, _Float16* __restrict__ S,
    const float* __restrict__ x, const float* __restrict__ cb,
    float* __restrict__ out, unsigned* __restrict__ cnt, int fused) {
  __shared__ __attribute__((aligned(16))) unsigned char sA[2][128 * 128];
  __shared__ __attribute__((aligned(16))) unsigned char sB[2][128 * 128];
  __shared__ int lastf;

  const int tid = threadIdx.x;
  // XCD-chunked swizzle (bijective, 512%8==0): A-panels + whole B L2-fit/XCD,
  // and all 8 blocks of a bm group land on one XCD.
  const int wg = blockIdx.x;
  const int sw = (wg & 7) * 64 + (wg >> 3);
  const int bm = sw >> 3;             // 0..63  (M tiles)
  const int bn = sw & 7;              // 0..7   (N tiles)
  const int m0 = bm * 128, n0 = bn * 128;
  const int wave = tid >> 6, lane = tid & 63;
  const int wm = wave & 1, wn = wave >> 1;
  const int quad = lane >> 4, l15 = lane & 15;

  floatx4 acc[4][4];
#pragma unroll
  for (int i = 0; i < 4; ++i)
#pragma unroll
    for (int j = 0; j < 4; ++j) acc[i][j] = (floatx4){0.f, 0.f, 0.f, 0.f};

  const int srow = wave * 32 + (lane >> 3);  // + n*8 per staging instr
  const int scol = (lane & 7) * 16;

  auto stage = [&](int kb, int b) {
    const int koff = kb * 128;
#pragma unroll
    for (int n = 0; n < 4; ++n) {
      GLOAD_LDS16(A8 + (size_t)(m0 + srow + n * 8) * DD + koff + scol,
                  &sA[b][(wave * 32 + n * 8) * 128]);
      GLOAD_LDS16(B8 + (size_t)(n0 + srow + n * 8) * DD + koff + scol,
                  &sB[b][(wave * 32 + n * 8) * 128]);
    }
  };
  auto compute = [&](int c) {
    intx8 af[4], bf[4];
#pragma unroll
    for (int i = 0; i < 4; ++i) {
      const int row = wm * 64 + i * 16 + l15;
      const int a0 = ((row << 7) + (quad << 5)) ^ ((row & 7) << 4);
      intx4 lo = *(const intx4*)&sA[c][a0];
      intx4 hi = *(const intx4*)&sA[c][a0 ^ 16];
      af[i][0] = lo[0]; af[i][1] = lo[1]; af[i][2] = lo[2]; af[i][3] = lo[3];
      af[i][4] = hi[0]; af[i][5] = hi[1]; af[i][6] = hi[2]; af[i][7] = hi[3];
    }
#pragma unroll
    for (int j = 0; j < 4; ++j) {
      const int row = wn * 64 + j * 16 + l15;
      const int a0 = ((row << 7) + (quad << 5)) ^ ((row & 7) << 4);
      intx4 lo = *(const intx4*)&sB[c][a0];
      intx4 hi = *(const intx4*)&sB[c][a0 ^ 16];
      bf[j][0] = lo[0]; bf[j][1] = lo[1]; bf[j][2] = lo[2]; bf[j][3] = lo[3];
      bf[j][4] = hi[0]; bf[j][5] = hi[1]; bf[j][6] = hi[2]; bf[j][7] = hi[3];
    }
#pragma unroll
    for (int i = 0; i < 4; ++i)
#pragma unroll
      for (int j = 0; j < 4; ++j)
        acc[i][j] = __builtin_amdgcn_mfma_scale_f32_16x16x128_f8f6f4(
            af[i], bf[j], acc[i][j], 0 /*A=fp8*/, 0 /*B=fp8*/,
            0, 0x7f7f7f7f, 0, 0x7f7f7f7f);  // E8M0 scales = 2^0
  };

  stage(0, 0);
  for (int kb = 0; kb < 8; ++kb) {
    asm volatile("s_waitcnt vmcnt(0)" ::: "memory");  // own tile-kb landed
    __builtin_amdgcn_s_barrier();   // all waves: tile kb visible, compute(kb-1) done
    if (kb < 7) stage(kb + 1, (kb + 1) & 1);  // into buf freed by compute(kb-1)
    __builtin_amdgcn_sched_barrier(0);
    compute(kb & 1);                // overlaps tile kb+1's loads in flight
  }

  // epilogue: write f16 approx scores
  float csv[4];
#pragma unroll
  for (int j = 0; j < 4; ++j) csv[j] = csqr[n0 + wn * 64 + j * 16 + l15];
#pragma unroll
  for (int i = 0; i < 4; ++i)
#pragma unroll
    for (int r = 0; r < 4; ++r) {
      const int row = m0 + wm * 64 + i * 16 + quad * 4 + r;  // C/D: col=lane&15, row=quad*4+reg
#pragma unroll
      for (int j = 0; j < 4; ++j) {
        const int col = n0 + wn * 64 + j * 16 + l15;
        S[(size_t)row * NK + col] = (_Float16)(csv[j] - 2.0f * acc[i][j][r]);
      }
    }

  if (!fused) return;

  // ---- fused refine: last-arriving block of each bm group owns its rows ----
  __threadfence();            // release: S tile visible agent-wide (L2 wb)
  __syncthreads();            // all threads' stores+fence done before the bump
  if (tid == 0) lastf = (atomicAdd(&cnt[bm], 1u) == 7u) ? 1 : 0;
  __syncthreads();
  if (!lastf) return;
  __threadfence();            // acquire: see the other 7 blocks' S tiles

  for (int rr = 0; rr < 32; ++rr)
    refine_row(m0 + wave * 32 + rr, lane, S, x, cb, out, 1);
}

// -------- standalone refine (fallback when d_ws is unusable) --------
__global__ __launch_bounds__(256) void k_refine(
    const _Float16* __restrict__ S, const float* __restrict__ x,
    const float* __restrict__ cb, float* __restrict__ out, int both) {
  const int wave = threadIdx.x >> 6, lane = threadIdx.x & 63;
  refine_row(blockIdx.x * 4 + wave, lane, S, x, cb, out, both);
}

// d2d copy lower output copy -> upper (only when S had to live in d_out's top)
__global__ void k_copy(const floatx4* __restrict__ src, floatx4* __restrict__ dst) {
  int i = blockIdx.x * 256 + threadIdx.x;
  __builtin_nontemporal_store(src[i], &dst[i]);
}

extern "C" void kernel_launch(void* const* d_in, const int* in_sizes, int n_in,
                              void* d_out, int out_size, void* d_ws, size_t ws_size,
                              hipStream_t stream) {
  const float* x = (const float*)d_in[0];
  const float* cb = (const float*)d_in[1];
  float* out = (float*)d_out;
  char* ob = (char*)d_out;

  const size_t MB = 1024 * 1024;
  // Fused path needs ALL scratch in d_ws: the fused refine writes outputs
  // while other bm groups are still screening, so no scratch may alias d_out.
  // Layout in ws: S [0,16MB) | csqr [16MB,+4KB) | cnt [+4KB,+256B) |
  //               A8 [17,25MB) | B8 [25,26MB)
  const bool ws_ok = ws_size >= 26 * MB;
  if (ws_ok) {
    char* wb = (char*)d_ws;
    _Float16* S = (_Float16*)wb;
    float* csqr = (float*)(wb + 16 * MB);
    unsigned* cnt = (unsigned*)(wb + 16 * MB + 4096);
    unsigned char* A8 = (unsigned char*)(wb + 17 * MB);
    unsigned char* B8 = (unsigned char*)(wb + 25 * MB);
    k_prep<<<2048 + 256, 256, 0, stream>>>(x, cb, A8, B8, csqr, cnt);
    k_screen<<<512, 256, 0, stream>>>(A8, B8, csqr, S, x, cb, out, cnt, 1);
  } else {
    // fallback: proven 3-kernel flow, scratch in d_out (dead-before-overwrite)
    unsigned char* A8 = (unsigned char*)(ob);            // [0,8MB)
    unsigned char* B8 = (unsigned char*)(ob + 8 * MB);   // [8,9MB)
    float* csqr = (float*)(ob + 9 * MB);
    unsigned* cnt = (unsigned*)(ob + 9 * MB + 4096);
    _Float16* S = (_Float16*)(ob + 48 * MB);             // upper-copy top half
    k_prep<<<2048 + 256, 256, 0, stream>>>(x, cb, A8, B8, csqr, cnt);
    k_screen<<<512, 256, 0, stream>>>(A8, B8, csqr, S, x, cb, out, cnt, 0);
    k_refine<<<2048, 256, 0, stream>>>(S, x, cb, out, 0);
    k_copy<<<8192, 256, 0, stream>>>((const floatx4*)out, (floatx4*)(ob + 32 * MB));
  }
}

// Round 8
// 123.239 us; speedup vs baseline: 2.4639x; 2.4639x over previous
//
#include <hip/hip_runtime.h>
#include <hip/hip_fp16.h>
#include <stdint.h>

// Problem constants (fixed by the reference):
#define MQ 8192   // N*C queries
#define NK 1024   // K codewords
#define DD 1024   // H*W
// fp8-e4m3 screen: pairwise score err sigma ~5 (fp8 quant of both operands
// over K=1024 + f16 score store) -> DELTA=32 ~ 6.4 sigma. Measured slow-path
// fraction ~30% (R7 FETCH arithmetic), costing ~1.6us. Do NOT shrink.
#define DELTA 32.0f

typedef _Float16 half8_t __attribute__((ext_vector_type(8)));
typedef float    floatx4 __attribute__((ext_vector_type(4)));
typedef int      intx4   __attribute__((ext_vector_type(4)));
typedef int      intx8   __attribute__((ext_vector_type(8)));

// async global->LDS, 16B per lane; LDS dest is wave-uniform base + lane*16
#define GLOAD_LDS16(gp, lp)                                                   \
  __builtin_amdgcn_global_load_lds(                                           \
      (const __attribute__((address_space(1))) void*)(gp),                    \
      (__attribute__((address_space(3))) void*)(lp), 16, 0, 0)

// ---------- prep: f32 -> fp8(e4m3) with PRE-SWIZZLED k-layout + csqr ----------
// Within each row's 128B K-chunk, byte b of the fp8 row is stored at
// b ^ ((row&7)<<4). Screen stages linearly (global_load_lds can't scatter) and
// un-XORs on the LDS read -> 16-way bank conflict becomes 2-way (free).
__global__ void k_prep(const float* __restrict__ x, const float* __restrict__ cb,
                       unsigned char* __restrict__ a8, unsigned char* __restrict__ b8,
                       float* __restrict__ csqr) {
  const int bid = blockIdx.x;
  const int t = threadIdx.x;
  if (bid < 2048) {
    // queries: thread converts 16 floats -> one 16B fp8 granule
    const int gid = bid * 256 + t;
    const int row = gid >> 6, g = gid & 63;
    const float4* src = (const float4*)(x + (size_t)row * DD + g * 16);
    int w[4];
#pragma unroll
    for (int q = 0; q < 4; ++q) {
      float4 v = src[q];
      int p = __builtin_amdgcn_cvt_pk_fp8_f32(v.x, v.y, 0, false);
      p = __builtin_amdgcn_cvt_pk_fp8_f32(v.z, v.w, p, true);
      w[q] = p;
    }
    intx4 o = {w[0], w[1], w[2], w[3]};
    const int doff = (g * 16) ^ ((row & 7) << 4);
    *(intx4*)(a8 + (size_t)row * DD + doff) = o;
  } else {
    // codewords: one wave per row (4 rows/block); fp8 + exact |c|^2 in double
    const int wv = t >> 6, lane = t & 63;
    const int k = (bid - 2048) * 4 + wv;
    const float4* src = (const float4*)(cb + (size_t)k * DD + lane * 16);
    double s = 0.0;
    int w[4];
#pragma unroll
    for (int q = 0; q < 4; ++q) {
      float4 v = src[q];
      s += (double)v.x * v.x + (double)v.y * v.y + (double)v.z * v.z + (double)v.w * v.w;
      int p = __builtin_amdgcn_cvt_pk_fp8_f32(v.x, v.y, 0, false);
      p = __builtin_amdgcn_cvt_pk_fp8_f32(v.z, v.w, p, true);
      w[q] = p;
    }
    intx4 o = {w[0], w[1], w[2], w[3]};
    const int doff = (lane * 16) ^ ((k & 7) << 4);
    *(intx4*)(b8 + (size_t)k * DD + doff) = o;
    for (int m = 32; m >= 1; m >>= 1) s += __shfl_xor(s, m, 64);
    if (lane == 0) csqr[k] = (float)(s - 1024.0);
  }
}

__device__ __forceinline__ unsigned sortable_u32(float f) {
  unsigned u = __float_as_uint(f);
  return (u & 0x80000000u) ? ~u : (u | 0x80000000u);
}

// ---------------- phase A: fp8 MX screen GEMM (K=128/instr, scales=1.0) -----
// S[m][n] = f16(csqr[n] - 2 * dot(x8[m], c8[n])) ; 128x128 tile, 4 waves.
// BK=128 -> 32KB/buffer, 2 buffers; counted single-depth prefetch (R4-proven).
// NEW: coalesced S epilogue — stage the 128x128 f16 tile in LDS (pitch 132,
// conflict-free: quad stride 264dw %32 = 8 -> quads hit disjoint bank octets)
// then write 256B-contiguous rows instead of 64 scalar 2B stores/thread.
__global__ __launch_bounds__(256) void k_screen(
    const unsigned char* __restrict__ A8, const unsigned char* __restrict__ B8,
    const float* __restrict__ csqr, _Float16* __restrict__ S) {
  // flat LDS, manually aliased: sA buf b = smem + b*16K; sB buf b = +32K.
  // epilogue reuses the whole region as a [128][132] f16 staging tile (33.8KB).
  __shared__ __attribute__((aligned(16))) unsigned char smem[65536];

  const int tid = threadIdx.x;
  // XCD-chunked swizzle (bijective, 512%8==0): A-panels + whole B L2-fit/XCD.
  const int wg = blockIdx.x;
  const int sw = (wg & 7) * 64 + (wg >> 3);
  const int bm = sw >> 3;             // 0..63  (M tiles)
  const int bn = sw & 7;              // 0..7   (N tiles)
  const int m0 = bm * 128, n0 = bn * 128;
  const int wave = tid >> 6, lane = tid & 63;
  const int wm = wave & 1, wn = wave >> 1;
  const int quad = lane >> 4, l15 = lane & 15;

  floatx4 acc[4][4];
#pragma unroll
  for (int i = 0; i < 4; ++i)
#pragma unroll
    for (int j = 0; j < 4; ++j) acc[i][j] = (floatx4){0.f, 0.f, 0.f, 0.f};

  const int srow = wave * 32 + (lane >> 3);  // + n*8 per staging instr
  const int scol = (lane & 7) * 16;

  auto stage = [&](int kb, int b) {
    const int koff = kb * 128;
    unsigned char* sa = smem + b * 16384;
    unsigned char* sb = smem + 32768 + b * 16384;
#pragma unroll
    for (int n = 0; n < 4; ++n) {
      GLOAD_LDS16(A8 + (size_t)(m0 + srow + n * 8) * DD + koff + scol,
                  sa + (wave * 32 + n * 8) * 128);
      GLOAD_LDS16(B8 + (size_t)(n0 + srow + n * 8) * DD + koff + scol,
                  sb + (wave * 32 + n * 8) * 128);
    }
  };
  auto compute = [&](int c) {
    const unsigned char* sa = smem + c * 16384;
    const unsigned char* sb = smem + 32768 + c * 16384;
    intx8 af[4], bf[4];
#pragma unroll
    for (int i = 0; i < 4; ++i) {
      const int row = wm * 64 + i * 16 + l15;
      const int a0 = ((row << 7) + (quad << 5)) ^ ((row & 7) << 4);
      intx4 lo = *(const intx4*)&sa[a0];
      intx4 hi = *(const intx4*)&sa[a0 ^ 16];
      af[i][0] = lo[0]; af[i][1] = lo[1]; af[i][2] = lo[2]; af[i][3] = lo[3];
      af[i][4] = hi[0]; af[i][5] = hi[1]; af[i][6] = hi[2]; af[i][7] = hi[3];
    }
#pragma unroll
    for (int j = 0; j < 4; ++j) {
      const int row = wn * 64 + j * 16 + l15;
      const int a0 = ((row << 7) + (quad << 5)) ^ ((row & 7) << 4);
      intx4 lo = *(const intx4*)&sb[a0];
      intx4 hi = *(const intx4*)&sb[a0 ^ 16];
      bf[j][0] = lo[0]; bf[j][1] = lo[1]; bf[j][2] = lo[2]; bf[j][3] = lo[3];
      bf[j][4] = hi[0]; bf[j][5] = hi[1]; bf[j][6] = hi[2]; bf[j][7] = hi[3];
    }
#pragma unroll
    for (int i = 0; i < 4; ++i)
#pragma unroll
      for (int j = 0; j < 4; ++j)
        acc[i][j] = __builtin_amdgcn_mfma_scale_f32_16x16x128_f8f6f4(
            af[i], bf[j], acc[i][j], 0 /*A=fp8*/, 0 /*B=fp8*/,
            0, 0x7f7f7f7f, 0, 0x7f7f7f7f);  // E8M0 scales = 2^0
  };

  stage(0, 0);
  for (int kb = 0; kb < 8; ++kb) {
    asm volatile("s_waitcnt vmcnt(0)" ::: "memory");  // own tile-kb landed
    __builtin_amdgcn_s_barrier();   // all waves: tile kb visible, compute(kb-1) done
    if (kb < 7) stage(kb + 1, (kb + 1) & 1);  // into buf freed by compute(kb-1)
    __builtin_amdgcn_sched_barrier(0);
    compute(kb & 1);                // overlaps tile kb+1's loads in flight
  }

  // ---- epilogue: repack scores through LDS, write S coalesced ----
  float csv[4];
#pragma unroll
  for (int j = 0; j < 4; ++j) csv[j] = csqr[n0 + wn * 64 + j * 16 + l15];

  __syncthreads();  // all LDS reads of the K-loop done before reuse
  _Float16* st = (_Float16*)smem;  // [128][132] f16, pitch 132 (conflict-free)
#pragma unroll
  for (int i = 0; i < 4; ++i)
#pragma unroll
    for (int r = 0; r < 4; ++r) {
      const int row = wm * 64 + i * 16 + quad * 4 + r;  // C/D: col=lane&15, row=quad*4+reg
#pragma unroll
      for (int j = 0; j < 4; ++j) {
        const int col = wn * 64 + j * 16 + l15;
        st[row * 132 + col] = (_Float16)(csv[j] - 2.0f * acc[i][j][r]);
      }
    }
  __syncthreads();

  // 2048 16B chunks (128 rows x 16); consecutive threads -> contiguous 256B rows
#pragma unroll
  for (int k = 0; k < 8; ++k) {
    const int c = tid + k * 256;
    const int row = c >> 4, col16 = c & 15;
    intx4 v = *(const intx4*)&st[row * 132 + col16 * 8];
    *(intx4*)&S[(size_t)(m0 + row) * NK + n0 + col16 * 8] = v;
  }
}

// -------- phase B: wave-per-row scan + exact fp32 refine + gather/write --------
// Capless candidate handling (R5 fix): popcount total via ballots; slow path
// re-iterates the ballot masks directly — correct for any nc.
__global__ __launch_bounds__(256) void k_refine(
    const _Float16* __restrict__ S, const float* __restrict__ x,
    const float* __restrict__ cb, float* __restrict__ out, int both) {
  const int wave = threadIdx.x >> 6, lane = threadIdx.x & 63;
  const int m = blockIdx.x * 4 + wave;

  // scan score row: 16 f16 per lane
  const half8_t* Srow = (const half8_t*)(S + (size_t)m * NK);
  half8_t s0 = Srow[lane * 2];
  half8_t s1 = Srow[lane * 2 + 1];
  float sc[16];
#pragma unroll
  for (int k = 0; k < 8; ++k) { sc[k] = (float)s0[k]; sc[8 + k] = (float)s1[k]; }
  float mn = sc[0];
#pragma unroll
  for (int k = 1; k < 16; ++k) mn = fminf(mn, sc[k]);
  for (int o = 1; o <= 32; o <<= 1) mn = fminf(mn, __shfl_xor(mn, o, 64));
  const float thr = mn + DELTA;

  // count candidates + remember the first (all wave-uniform; >=1 guaranteed)
  int total = 0, first = -1;
#pragma unroll
  for (int s = 0; s < 16; ++s) {
    unsigned long long msk = __ballot(sc[s] <= thr);
    if (first < 0 && msk) first = __builtin_ctzll(msk) * 16 + s;
    total += __popcll(msk);
  }

  int widx;
  if (total == 1) {
    widx = first;  // unique winner: skip x re-read + exact refine entirely
  } else {
    // x row in registers: lane covers floats [q*256 + lane*4, +4)
    const float4* xr4 = (const float4*)(x + (size_t)m * DD);
    float4 xr[4];
#pragma unroll
    for (int q = 0; q < 4; ++q) xr[q] = xr4[q * 64 + lane];

    // exact fp32 refine — iterate ballot masks directly (no cap, no drop)
    unsigned long long best = ~0ULL;
    for (int s = 0; s < 16; ++s) {
      unsigned long long msk = __ballot(sc[s] <= thr);
      while (msk) {
        int l = __builtin_ctzll(msk);
        msk &= msk - 1;
        const int cnd = l * 16 + s;  // lane l holds cols l*16 + s
        const float4* c4 = (const float4*)(cb + (size_t)cnd * DD);
        float d = 0.f;
#pragma unroll
        for (int q = 0; q < 4; ++q) {
          float4 v = c4[q * 64 + lane];
          float dx = xr[q].x - v.x, dy = xr[q].y - v.y;
          float dz = xr[q].z - v.z, dw = xr[q].w - v.w;
          d += dx * dx + dy * dy + dz * dz + dw * dw;
        }
        for (int o = 1; o <= 32; o <<= 1) d += __shfl_xor(d, o, 64);
        unsigned long long key =
            ((unsigned long long)sortable_u32(d) << 32) | (unsigned)cnd;
        best = key < best ? key : best;  // ties -> lowest index (np argmin)
      }
    }
    widx = (int)(best & 0xFFFFFFFFULL);
  }

  // gather winner (cb is 4MB -> L2/L3-hot), write output(s) nontemporally
  const floatx4* w4 = (const floatx4*)(cb + (size_t)widx * DD);
  floatx4* o0 = (floatx4*)(out + (size_t)m * DD);
  floatx4* o1 = (floatx4*)(out + (size_t)(m + MQ) * DD);
#pragma unroll
  for (int q = 0; q < 4; ++q) {
    floatx4 v = w4[q * 64 + lane];
    __builtin_nontemporal_store(v, &o0[q * 64 + lane]);
    if (both) __builtin_nontemporal_store(v, &o1[q * 64 + lane]);
  }
}

// d2d copy lower output copy -> upper (only when S had to live in d_out's top)
__global__ void k_copy(const floatx4* __restrict__ src, floatx4* __restrict__ dst) {
  int i = blockIdx.x * 256 + threadIdx.x;
  __builtin_nontemporal_store(src[i], &dst[i]);
}

extern "C" void kernel_launch(void* const* d_in, const int* in_sizes, int n_in,
                              void* d_out, int out_size, void* d_ws, size_t ws_size,
                              hipStream_t stream) {
  const float* x = (const float*)d_in[0];
  const float* cb = (const float*)d_in[1];
  float* out = (float*)d_out;
  char* ob = (char*)d_out;

  const size_t MB = 1024 * 1024;
  // fp8 scratch lives in d_out (dead before any output write):
  //   A8 [0,8MB)  fp8 queries (pre-swizzled)
  //   B8 [8,9MB)  fp8 codewords (pre-swizzled)
  unsigned char* A8 = (unsigned char*)(ob);
  unsigned char* B8 = (unsigned char*)(ob + 8 * MB);

  // S (16MB) + csqr (4KB): prefer d_ws (harness restores it every iteration
  // whether we touch it or not — measured R3). Fallback: S in d_out[48,64MB).
  const bool ws_ok = ws_size >= 16 * MB + 4096;
  _Float16* S;
  float* csqr;
  if (ws_ok) {
    S = (_Float16*)d_ws;
    csqr = (float*)((char*)d_ws + 16 * MB);
  } else {
    S = (_Float16*)(ob + 48 * MB);
    csqr = (float*)(ob + 9 * MB);
  }

  k_prep<<<2048 + 256, 256, 0, stream>>>(x, cb, A8, B8, csqr);
  k_screen<<<512, 256, 0, stream>>>(A8, B8, csqr, S);
  k_refine<<<2048, 256, 0, stream>>>(S, x, cb, out, ws_ok ? 1 : 0);
  if (!ws_ok) k_copy<<<8192, 256, 0, stream>>>((const floatx4*)out, (floatx4*)(ob + 32 * MB));
}